// Round 1
// baseline (472.158 us; speedup 1.0000x reference)
//
#include <hip/hip_runtime.h>

// LengthRegulator: B=64, T=512, D=384, MAX_LEN=4096
//   csum = cumsum(duration, axis=1); mel_len = csum[:, -1]
//   idx[b,p] = searchsorted(csum[b], p, side='right'), clipped to T-1
//   out[b,p,:] = x[b, idx[b,p], :] if p < mel_len[b] else 0
// Output buffer layout (flat float32): [B*ML*D] out, then [B] mel_len (as float).

#define T_DIM 512
#define D_DIM 384
#define D4    (D_DIM / 4)   // 96 float4 per row
#define ROWS  32            // output rows per block
#define BLOCK 512

__global__ __launch_bounds__(BLOCK) void length_regulator_kernel(
    const float* __restrict__ x,        // [B, T, D]
    const int*   __restrict__ duration, // [B, T]
    float*       __restrict__ out,      // [B*ML*D] ++ [B]
    int B, int ML)
{
    __shared__ int s_csum[T_DIM];
    __shared__ int s_idx[ROWS];

    const int chunks_per_b = ML / ROWS;
    const int b     = blockIdx.x / chunks_per_b;
    const int chunk = blockIdx.x % chunks_per_b;
    const int row0  = chunk * ROWS;
    const int tid   = threadIdx.x;

    // Load this batch's durations (2 KB; L2-cached across the 128 blocks/batch)
    s_csum[tid] = duration[b * T_DIM + tid];
    __syncthreads();

    // Inclusive scan (Hillis-Steele): read old neighbor, barrier, add, barrier.
    for (int off = 1; off < T_DIM; off <<= 1) {
        int v = (tid >= off) ? s_csum[tid - off] : 0;
        __syncthreads();
        s_csum[tid] += v;
        __syncthreads();
    }
    const int mel = s_csum[T_DIM - 1];

    // searchsorted(csum, pos, side='right') for the 32 rows this block owns
    if (tid < ROWS) {
        const int pos = row0 + tid;
        int idx;
        if (pos >= mel) {
            idx = -1;  // masked row -> zeros
        } else {
            int lo = 0, hi = T_DIM;
            while (lo < hi) {
                int mid = (lo + hi) >> 1;
                if (s_csum[mid] <= pos) lo = mid + 1; else hi = mid;
            }
            idx = (lo < T_DIM - 1) ? lo : (T_DIM - 1);
        }
        s_idx[tid] = idx;
    }
    __syncthreads();

    // Copy 32 rows x 96 float4 = 3072 float4, contiguous across the chunk.
    const float4* __restrict__ x4   = (const float4*)x;
    float4*       __restrict__ out4 = (float4*)out;
    const float4 zero = make_float4(0.f, 0.f, 0.f, 0.f);

    const long long out_base = ((long long)b * ML + row0) * D4;
    const long long x_base   = (long long)b * T_DIM * D4;

    #pragma unroll
    for (int i = 0; i < (ROWS * D4) / BLOCK; ++i) {
        const int flat = tid + i * BLOCK;
        const int r = flat / D4;            // constant divisor -> magic mul
        const int j = flat - r * D4;
        const int t = s_idx[r];
        float4 v = (t < 0) ? zero : x4[x_base + (long long)t * D4 + j];
        out4[out_base + flat] = v;
    }

    // mel_len output, stored as float (harness reads whole buffer as fp32)
    if (chunk == 0 && tid == 0) {
        out[(long long)B * ML * D_DIM + b] = (float)mel;
    }
}

extern "C" void kernel_launch(void* const* d_in, const int* in_sizes, int n_in,
                              void* d_out, int out_size, void* d_ws, size_t ws_size,
                              hipStream_t stream) {
    const float* x   = (const float*)d_in[0];
    const int*   dur = (const int*)d_in[1];
    float*       out = (float*)d_out;

    const int B  = in_sizes[1] / T_DIM;                 // 64
    const int ML = (out_size - B) / (B * D_DIM);        // 4096

    const int grid = B * (ML / ROWS);                   // 8192 blocks
    hipLaunchKernelGGL(length_regulator_kernel, dim3(grid), dim3(BLOCK), 0, stream,
                       x, dur, out, B, ML);
}

// Round 2
// 439.737 us; speedup vs baseline: 1.0737x; 1.0737x over previous
//
#include <hip/hip_runtime.h>

// LengthRegulator: B=64, T=512, D=384, MAX_LEN=4096
// Kernel A (64 blocks): per-batch cumsum scan -> idx[b,p] table in d_ws, mel_len to out tail.
// Kernel B (8192 blocks): pure gather/copy, no LDS, no barriers, nontemporal stores.
// Output buffer layout (flat float32): [B*ML*D] out, then [B] mel_len (as float).

#define T_DIM 512
#define D_DIM 384
#define D4    (D_DIM / 4)   // 96 float4 per row
#define ROWS  32            // output rows per copy-block
#define BLOCK 512
#define ITER  ((ROWS * D4) / BLOCK)  // 6

typedef float vfloat4 __attribute__((ext_vector_type(4)));

__global__ __launch_bounds__(BLOCK) void lr_scan_idx_kernel(
    const int* __restrict__ duration,  // [B, T]
    int*       __restrict__ idx,       // [B, ML]  (d_ws)
    float*     __restrict__ mel_out,   // [B] at out tail
    int ML)
{
    __shared__ int s_csum[T_DIM];
    const int b   = blockIdx.x;
    const int tid = threadIdx.x;

    s_csum[tid] = duration[b * T_DIM + tid];
    __syncthreads();

    // Inclusive scan (Hillis-Steele) — runs once per batch (64 blocks total).
    for (int off = 1; off < T_DIM; off <<= 1) {
        int v = (tid >= off) ? s_csum[tid - off] : 0;
        __syncthreads();
        s_csum[tid] += v;
        __syncthreads();
    }
    const int mel = s_csum[T_DIM - 1];
    if (tid == 0) mel_out[b] = (float)mel;

    // idx[b,p] = searchsorted(csum, p, side='right') clipped, or -1 if masked.
    for (int p = tid; p < ML; p += BLOCK) {
        int v;
        if (p >= mel) {
            v = -1;
        } else {
            int lo = 0, hi = T_DIM;
            while (lo < hi) {
                int mid = (lo + hi) >> 1;
                if (s_csum[mid] <= p) lo = mid + 1; else hi = mid;
            }
            v = (lo < T_DIM - 1) ? lo : (T_DIM - 1);
        }
        idx[b * ML + p] = v;
    }
}

__global__ __launch_bounds__(BLOCK) void lr_copy_kernel(
    const float* __restrict__ x,    // [B, T, D]
    const int*   __restrict__ idx,  // [B, ML]
    float*       __restrict__ out,  // [B, ML, D]
    int ML)
{
    const int chunks_per_b = ML / ROWS;
    const int b     = blockIdx.x / chunks_per_b;
    const int chunk = blockIdx.x % chunks_per_b;
    const int row0  = chunk * ROWS;
    const int tid   = threadIdx.x;

    const vfloat4* __restrict__ x4   = (const vfloat4*)x;
    vfloat4*       __restrict__ out4 = (vfloat4*)out;

    const long long out_base = ((long long)b * ML + row0) * D4;
    const long long x_base   = (long long)b * T_DIM * D4;
    const int* __restrict__ idx_b = idx + b * ML + row0;

    #pragma unroll
    for (int i = 0; i < ITER; ++i) {
        const int flat = tid + i * BLOCK;
        const int r = flat / D4;            // constant divisor -> magic mul
        const int j = flat - r * D4;
        const int t = idx_b[r];             // 16 lanes share one address -> 1 cache line
        vfloat4 v = (vfloat4)(0.f, 0.f, 0.f, 0.f);
        if (t >= 0) v = x4[x_base + (long long)t * D4 + j];
        __builtin_nontemporal_store(v, &out4[out_base + flat]);  // write-once stream
    }
}

extern "C" void kernel_launch(void* const* d_in, const int* in_sizes, int n_in,
                              void* d_out, int out_size, void* d_ws, size_t ws_size,
                              hipStream_t stream) {
    const float* x   = (const float*)d_in[0];
    const int*   dur = (const int*)d_in[1];
    float*       out = (float*)d_out;
    int*         idx = (int*)d_ws;

    const int B  = in_sizes[1] / T_DIM;                 // 64
    const int ML = (out_size - B) / (B * D_DIM);        // 4096

    float* mel_out = out + (long long)B * ML * D_DIM;

    hipLaunchKernelGGL(lr_scan_idx_kernel, dim3(B), dim3(BLOCK), 0, stream,
                       dur, idx, mel_out, ML);

    const int grid = B * (ML / ROWS);                   // 8192 blocks
    hipLaunchKernelGGL(lr_copy_kernel, dim3(grid), dim3(BLOCK), 0, stream,
                       x, idx, out, ML);
}

// Round 3
// 433.376 us; speedup vs baseline: 1.0895x; 1.0147x over previous
//
#include <hip/hip_runtime.h>

// LengthRegulator: B=64, T=512, D=384, MAX_LEN=4096
// Kernel A (B blocks): per-batch cumsum -> scatter idx[b,p] into d_ws (+tail -1), mel_len to out tail.
// Kernel B (B*128 blocks): pure gather/copy. Swizzled so blockIdx%8 == b%8 (batch pinned to one XCD
//   under round-robin dispatch -> x slice stays in that XCD's L2, no 8x cross-XCD re-read).
// Output layout (flat float32): [B*ML*D] out, then [B] mel_len (as float).

#define T_DIM 512
#define D_DIM 384
#define D4    (D_DIM / 4)   // 96 float4 per row
#define ROWS  32            // output rows per copy-block
#define BLOCK 512
#define ITER  ((ROWS * D4) / BLOCK)  // 6

typedef float vfloat4 __attribute__((ext_vector_type(4)));

__global__ __launch_bounds__(BLOCK) void lr_scan_idx_kernel(
    const int* __restrict__ duration,  // [B, T]
    int*       __restrict__ idx,       // [B, ML]  (d_ws)
    float*     __restrict__ mel_out,   // [B] at out tail
    int ML)
{
    __shared__ int s_csum[T_DIM];
    const int b   = blockIdx.x;
    const int tid = threadIdx.x;

    s_csum[tid] = duration[b * T_DIM + tid];
    __syncthreads();

    // Inclusive Hillis-Steele scan (once per batch; 64 blocks total).
    for (int off = 1; off < T_DIM; off <<= 1) {
        int v = (tid >= off) ? s_csum[tid - off] : 0;
        __syncthreads();
        s_csum[tid] += v;
        __syncthreads();
    }
    const int mel = s_csum[T_DIM - 1];
    if (tid == 0) mel_out[b] = (float)mel;

    int* __restrict__ idx_b = idx + b * ML;

    // Scatter: positions [csum[t-1], csum[t]) get value t. Adjacent lanes write
    // adjacent ranges -> coalesces. (p < mel implies t <= T-1, so no clip needed.)
    const int start = (tid == 0) ? 0 : s_csum[tid - 1];
    const int end   = s_csum[tid];
    for (int p = start; p < end; ++p) idx_b[p] = tid;

    // Tail: masked positions [mel, ML) -> -1 (coalesced).
    for (int p = mel + tid; p < ML; p += BLOCK) idx_b[p] = -1;
}

__global__ __launch_bounds__(BLOCK) void lr_copy_kernel(
    const float* __restrict__ x,    // [B, T, D]
    const int*   __restrict__ idx,  // [B, ML]
    float*       __restrict__ out,  // [B, ML, D]
    int B, int ML)
{
    // Swizzle: b fastest so XCD = blockIdx % 8 == b % 8 (B multiple of 8).
    const int b     = blockIdx.x % B;
    const int chunk = blockIdx.x / B;
    const int row0  = chunk * ROWS;
    const int tid   = threadIdx.x;

    const vfloat4* __restrict__ x4   = (const vfloat4*)x;
    vfloat4*       __restrict__ out4 = (vfloat4*)out;

    const long long out_base = ((long long)b * ML + row0) * D4;
    const long long x_base   = (long long)b * T_DIM * D4;
    const int* __restrict__ idx_b = idx + b * ML + row0;

    #pragma unroll
    for (int i = 0; i < ITER; ++i) {
        const int flat = tid + i * BLOCK;
        const int r = flat / D4;            // constant divisor -> magic mul
        const int j = flat - r * D4;
        const int t = idx_b[r];             // broadcast within 16-lane groups
        vfloat4 v = (vfloat4)(0.f, 0.f, 0.f, 0.f);
        if (t >= 0) v = x4[x_base + (long long)t * D4 + j];
        out4[out_base + flat] = v;          // plain store (nt removed: A/B vs R2)
    }
}

extern "C" void kernel_launch(void* const* d_in, const int* in_sizes, int n_in,
                              void* d_out, int out_size, void* d_ws, size_t ws_size,
                              hipStream_t stream) {
    const float* x   = (const float*)d_in[0];
    const int*   dur = (const int*)d_in[1];
    float*       out = (float*)d_out;
    int*         idx = (int*)d_ws;

    const int B  = in_sizes[1] / T_DIM;                 // 64
    const int ML = (out_size - B) / (B * D_DIM);        // 4096

    float* mel_out = out + (long long)B * ML * D_DIM;

    hipLaunchKernelGGL(lr_scan_idx_kernel, dim3(B), dim3(BLOCK), 0, stream,
                       dur, idx, mel_out, ML);

    const int grid = B * (ML / ROWS);                   // 8192 blocks
    hipLaunchKernelGGL(lr_copy_kernel, dim3(grid), dim3(BLOCK), 0, stream,
                       x, idx, out, B, ML);
}